// Round 1
// baseline (864.037 us; speedup 1.0000x reference)
//
#include <hip/hip_runtime.h>

// ---------------------------------------------------------------------------
// Talking-heads attention, fused. B=2, N=M=2048, D=1024, H=16, dh=64.
// R5: occupancy attack. attn split into (a) LDS-free denom kernel (j-split,
// 512 blocks, 2/CU, atomicAdd partial row-sums) and (b) pass2 kernel with
// LDS shrunk 108->72 KB (talk MFMA K=16 via 16x16x16bf16_1k, P stride 18,
// no P zero-init) + j-split grid 512 -> 2 blocks/CU = 32 waves/CU.
// Output combined via coalesced f32 atomicAdd into memset-zeroed out.
// exp -> exp2 with log2(e) folded into the Q projection scale.
// ---------------------------------------------------------------------------

typedef __attribute__((ext_vector_type(8))) short short8;
typedef __attribute__((ext_vector_type(4))) short short4v;
typedef __attribute__((ext_vector_type(4))) float float4v;
typedef unsigned short u16;

#define MFMA16(a, b, c) __builtin_amdgcn_mfma_f32_16x16x32_bf16((a), (b), (c), 0, 0, 0)
// K=16 talk MFMA: A,B are 4 bf16 (short4v). A[i=l15][k=lq*4+t], B[k][j=l15].
#define MFMA16K16(a, b, c) __builtin_amdgcn_mfma_f32_16x16x16bf16_1k((a), (b), (c), 0, 0, 0)

__device__ inline u16 f2bf(float f) {  // RNE f32->bf16 (inputs finite)
  unsigned u = __float_as_uint(f);
  u += 0x7FFFu + ((u >> 16) & 1u);
  return (u16)(u >> 16);
}

__device__ inline float fexp2(float x) { return __builtin_amdgcn_exp2f(x); }

// ---------------------------- cast kernel ----------------------------------
__global__ __launch_bounds__(256) void cast_bf16(const float* __restrict__ in,
                                                 u16* __restrict__ out, int n) {
  int i = (blockIdx.x * 256 + threadIdx.x) * 8;
  if (i + 8 > n) return;
  float4v f0 = *(const float4v*)(in + i);
  float4v f1 = *(const float4v*)(in + i + 4);
  short8 o;
  o[0] = (short)f2bf(f0[0]); o[1] = (short)f2bf(f0[1]);
  o[2] = (short)f2bf(f0[2]); o[3] = (short)f2bf(f0[3]);
  o[4] = (short)f2bf(f1[0]); o[5] = (short)f2bf(f1[1]);
  o[6] = (short)f2bf(f1[2]); o[7] = (short)f2bf(f1[3]);
  *(short8*)(out + i) = o;
}

// ------------------------ projection GEMM ----------------------------------
template <int MODE>
__global__ __launch_bounds__(256, 4) void gemm_bt(const u16* __restrict__ A,
                                                  const u16* __restrict__ W,
                                                  u16* __restrict__ out0,
                                                  u16* __restrict__ out1) {
  __shared__ u16 As[64][40];
  __shared__ u16 Ws[64][40];
  const int t = threadIdx.x;
  const int wave = t >> 6, l = t & 63, l15 = l & 15, lq = l >> 4;
  const int r0 = blockIdx.x * 64, c0 = blockIdx.y * 64;
  const int srow = t >> 2, sch = t & 3;
  const u16* ag = A + (r0 + srow) * 1024 + sch * 8;
  const u16* wg = W + (c0 + srow) * 1024 + sch * 8;

  float4v acc[4];
#pragma unroll
  for (int i = 0; i < 4; ++i) acc[i] = (float4v){0.f, 0.f, 0.f, 0.f};

  short8 av = *(const short8*)ag;
  short8 wv = *(const short8*)wg;
  for (int kt = 0; kt < 32; ++kt) {
    __syncthreads();
    *(short8*)&As[srow][sch * 8] = av;
    *(short8*)&Ws[srow][sch * 8] = wv;
    __syncthreads();
    if (kt < 31) {
      av = *(const short8*)(ag + (kt + 1) * 32);
      wv = *(const short8*)(wg + (kt + 1) * 32);
    }
    short8 af = *(const short8*)&As[wave * 16 + l15][lq * 8];
#pragma unroll
    for (int fn = 0; fn < 4; ++fn) {
      short8 bf = *(const short8*)&Ws[fn * 16 + l15][lq * 8];
      acc[fn] = MFMA16(af, bf, acc[fn]);
    }
  }
#pragma unroll
  for (int fn = 0; fn < 4; ++fn) {
#pragma unroll
    for (int r = 0; r < 4; ++r) {
      int row = r0 + wave * 16 + lq * 4 + r;
      int col = c0 + fn * 16 + l15;
      int b = row >> 11, n = row & 2047;
      float v = acc[fn][r];
      if (MODE == 0) {
        // dh^-0.5 * log2(e): softmax done in base 2 (v_exp_f32 is 2^x)
        v *= 0.125f * 1.44269504088896f;
        int h = col >> 6, d = col & 63;
        out0[(((b * 16 + h) * 2048 + n) << 6) + d] = f2bf(v);
      } else {
        if (col < 1024) {
          int h = col >> 6, d = col & 63;
          out0[(((b * 16 + h) * 2048 + n) << 6) + d] = f2bf(v);
        } else {
          int cc = col - 1024;
          int h = cc >> 6, d = cc & 63;
          out1[(((b * 16 + h) * 2048 + n) << 6) + d] = f2bf(v);
        }
      }
    }
  }
}

// --------------------------- V transpose -----------------------------------
__global__ __launch_bounds__(256) void transpose_v(const u16* __restrict__ vh,
                                                   u16* __restrict__ vt) {
  __shared__ u16 tile[64][72];
  const int t = threadIdx.x;
  const int j0 = blockIdx.x * 64, h = blockIdx.y, b = blockIdx.z;
  const u16* src = vh + (((b * 16 + h) * 2048 + j0) << 6);
  int row = t >> 2, c = t & 3;
  short8 v0 = *(const short8*)(src + row * 64 + c * 8);
  short8 v1 = *(const short8*)(src + row * 64 + (c + 4) * 8);
  *(short8*)&tile[row][c * 8] = v0;
  *(short8*)&tile[row][(c + 4) * 8] = v1;
  __syncthreads();
  int d = t >> 2, jc = t & 3;
  short8 o0, o1;
#pragma unroll
  for (int jj = 0; jj < 8; ++jj) o0[jj] = (short)tile[jc * 16 + jj][d];
#pragma unroll
  for (int jj = 0; jj < 8; ++jj) o1[jj] = (short)tile[jc * 16 + 8 + jj][d];
  u16* dst = vt + ((b * 16 + h) * 64 + d) * 2048 + j0 + jc * 16;
  *(short8*)dst = o0;
  *(short8*)(dst + 8) = o1;
}

// ----------------------- softmax denominators ------------------------------
// grid (itile=128, jhalf=2, b=2) = 512 blocks, 16 waves, NO LDS, no barriers.
// 2 blocks/CU = 8 waves/SIMD. Partial row-sums atomicAdd'ed into lsum[bh][i].
__global__ __launch_bounds__(1024, 8) void attn_denom(
    const u16* __restrict__ qh, const u16* __restrict__ kh,
    float* __restrict__ lsum) {
  const int tid = threadIdx.x;
  const int wv = tid >> 6;  // wave id == head
  const int l = tid & 63, l15 = l & 15, lq = l >> 4;
  const int i0 = blockIdx.x * 16;
  const int jh = blockIdx.y;
  const int b = blockIdx.z;
  const int bh = b * 16 + wv;

  const u16* qbase = qh + ((bh * 2048 + i0) << 6);
  short8 qf0 = *(const short8*)(qbase + l15 * 64 + lq * 8);
  short8 qf1 = *(const short8*)(qbase + l15 * 64 + 32 + lq * 8);
  const u16* kbase = kh + ((bh * 2048 + jh * 1024) << 6);

  float ps0 = 0.f, ps1 = 0.f, ps2 = 0.f, ps3 = 0.f;
  short8 k00 = *(const short8*)(kbase + l15 * 64 + lq * 8);
  short8 k01 = *(const short8*)(kbase + l15 * 64 + 32 + lq * 8);
  short8 k10 = *(const short8*)(kbase + (16 + l15) * 64 + lq * 8);
  short8 k11 = *(const short8*)(kbase + (16 + l15) * 64 + 32 + lq * 8);
  for (int jt = 0; jt < 32; ++jt) {
    short8 n00, n01, n10, n11;
    if (jt < 31) {
      const u16* kp = kbase + (((jt + 1) * 32) << 6);
      n00 = *(const short8*)(kp + l15 * 64 + lq * 8);
      n01 = *(const short8*)(kp + l15 * 64 + 32 + lq * 8);
      n10 = *(const short8*)(kp + (16 + l15) * 64 + lq * 8);
      n11 = *(const short8*)(kp + (16 + l15) * 64 + 32 + lq * 8);
    }
    float4v s0 = {0.f, 0.f, 0.f, 0.f}, s1 = {0.f, 0.f, 0.f, 0.f};
    s0 = MFMA16(qf0, k00, s0);
    s0 = MFMA16(qf1, k01, s0);
    s1 = MFMA16(qf0, k10, s1);
    s1 = MFMA16(qf1, k11, s1);
    ps0 += fexp2(s0[0]) + fexp2(s1[0]);
    ps1 += fexp2(s0[1]) + fexp2(s1[1]);
    ps2 += fexp2(s0[2]) + fexp2(s1[2]);
    ps3 += fexp2(s0[3]) + fexp2(s1[3]);
    k00 = n00; k01 = n01; k10 = n10; k11 = n11;
  }
#pragma unroll
  for (int d = 1; d < 16; d <<= 1) {
    ps0 += __shfl_xor(ps0, d);
    ps1 += __shfl_xor(ps1, d);
    ps2 += __shfl_xor(ps2, d);
    ps3 += __shfl_xor(ps3, d);
  }
  if (l15 == 0) {
    float* lp = lsum + bh * 2048 + i0 + lq * 4;
    atomicAdd(lp + 0, ps0);
    atomicAdd(lp + 1, ps1);
    atomicAdd(lp + 2, ps2);
    atomicAdd(lp + 3, ps3);
  }
}

// ------------------------- fused attention pass 2 --------------------------
// grid (itile=128, jhalf=2, b=2) = 512 blocks, 16 waves (wave == head).
// LDS 72 KB -> 2 blocks/CU = 32 waves/CU. One barrier per j-tile; P,Y
// double-buffered; PV lags one iteration. Talk MFMA is K=16 (no zero pad).
// Partial outputs atomicAdd'ed into zeroed out (2 adds/address, coalesced).
__global__ __launch_bounds__(1024, 8) void attn_pass2(
    const u16* __restrict__ qh, const u16* __restrict__ kh,
    const u16* __restrict__ vt, const float* __restrict__ wtalk,
    const float* __restrict__ gamma, const float* __restrict__ beta,
    const float* __restrict__ lsum, float* __restrict__ out) {
  __shared__ u16 P_lds[2][512 * 18];      // [buf][e=i*32+jl][18]; cols 0..15
  __shared__ u16 Y_lds[2][16 * 16 * 36];  // [buf][g*16+i][36]

  const int tid = threadIdx.x;
  const int wv = tid >> 6;  // wave id == head
  const int l = tid & 63, l15 = l & 15, lq = l >> 4;
  const int i0 = blockIdx.x * 16;
  const int jh = blockIdx.y;
  const int b = blockIdx.z;
  const int bh = b * 16 + wv;

  // Wtalk A-fragment for K=16 MFMA: A[g=l15][h=lq*4+t]
  short4v wfrag;
#pragma unroll
  for (int t4 = 0; t4 < 4; ++t4)
    wfrag[t4] = (short)f2bf(wtalk[l15 * 16 + lq * 4 + t4]);
  float gam[4], bet[4];
#pragma unroll
  for (int r = 0; r < 4; ++r) {
    gam[r] = gamma[lq * 4 + r];
    bet[r] = beta[lq * 4 + r];
  }

  const u16* qbase = qh + ((bh * 2048 + i0) << 6);
  short8 qf0 = *(const short8*)(qbase + l15 * 64 + lq * 8);
  short8 qf1 = *(const short8*)(qbase + l15 * 64 + 32 + lq * 8);
  const u16* kbase = kh + ((bh * 2048 + jh * 1024) << 6);
  const u16* vbase = vt + (bh * 64) * 2048 + jh * 1024;

  // bias: -log2(denominator), P = 2^(s + bc)
  float bc[4];
#pragma unroll
  for (int r = 0; r < 4; ++r)
    bc[r] = -__builtin_amdgcn_logf(lsum[bh * 2048 + i0 + lq * 4 + r]);

  float4v acc0 = {0.f, 0.f, 0.f, 0.f}, acc1 = acc0, acc2 = acc0, acc3 = acc0;
  short8 kc00 = *(const short8*)(kbase + l15 * 64 + lq * 8);
  short8 kc01 = *(const short8*)(kbase + l15 * 64 + 32 + lq * 8);
  short8 kc10 = *(const short8*)(kbase + (16 + l15) * 64 + lq * 8);
  short8 kc11 = *(const short8*)(kbase + (16 + l15) * 64 + 32 + lq * 8);
  short8 v0, v1, v2, v3;  // V for the *previous* tile (PV lags by 1)

  for (int jt = 0; jt <= 32; ++jt) {
    const int buf = jt & 1, pbuf = (jt - 1) & 1;
    if (jt >= 1) {
      const u16* vp = vbase + (jt - 1) * 32 + lq * 8;
      v0 = *(const short8*)(vp + (l15)*2048);
      v1 = *(const short8*)(vp + (16 + l15) * 2048);
      v2 = *(const short8*)(vp + (32 + l15) * 2048);
      v3 = *(const short8*)(vp + (48 + l15) * 2048);
    }
    short8 kn00, kn01, kn10, kn11;
    if (jt + 1 < 32) {
      const u16* kp = kbase + (((jt + 1) * 32) << 6);
      kn00 = *(const short8*)(kp + l15 * 64 + lq * 8);
      kn01 = *(const short8*)(kp + l15 * 64 + 32 + lq * 8);
      kn10 = *(const short8*)(kp + (16 + l15) * 64 + lq * 8);
      kn11 = *(const short8*)(kp + (16 + l15) * 64 + 32 + lq * 8);
    }
    if (jt < 32) {
      float4v s0 = {0.f, 0.f, 0.f, 0.f}, s1 = {0.f, 0.f, 0.f, 0.f};
      s0 = MFMA16(qf0, kc00, s0);
      s0 = MFMA16(qf1, kc01, s0);
      s1 = MFMA16(qf0, kc10, s1);
      s1 = MFMA16(qf1, kc11, s1);
      // P = 2^(S - log2 l) -> bf16 -> P_lds[buf][e][wv] (stride 18, no pad)
      int ebase = lq * 128 + l15;
#pragma unroll
      for (int r = 0; r < 4; ++r) {
        float p0 = fexp2(s0[r] + bc[r]);
        float p1 = fexp2(s1[r] + bc[r]);
        P_lds[buf][(ebase + r * 32) * 18 + wv] = f2bf(p0);
        P_lds[buf][(ebase + r * 32 + 16) * 18 + wv] = f2bf(p1);
      }
    }
    __syncthreads();  // the only barrier: P(jt) visible; Y(jt-1) visible
    if (jt < 32) {
      // talk (K=16): wave wv covers e in [wv*32, wv*32+32), i.e. i == wv
      float4v t0 = {0.f, 0.f, 0.f, 0.f}, t1 = {0.f, 0.f, 0.f, 0.f};
      {
        const u16* prow = &P_lds[buf][(wv * 32 + l15) * 18 + (lq << 2)];
        // stride 18 u16 => byte ≡ 4 (mod 8) possible: load as 2x b32
        union { int i2[2]; short4v s4; } u0, u1;
        u0.i2[0] = *(const int*)(prow);
        u0.i2[1] = *(const int*)(prow + 2);
        u1.i2[0] = *(const int*)(prow + 16 * 18);
        u1.i2[1] = *(const int*)(prow + 16 * 18 + 2);
        t0 = MFMA16K16(wfrag, u0.s4, t0);
        t1 = MFMA16K16(wfrag, u1.s4, t1);
      }
      // head-LN per (i,j) column, write Y bf16 to Y_lds[buf]
#pragma unroll
      for (int c2 = 0; c2 < 2; ++c2) {
        float4v tt = c2 ? t1 : t0;
        float sum = tt[0] + tt[1] + tt[2] + tt[3];
        sum += __shfl_xor(sum, 16);
        sum += __shfl_xor(sum, 32);
        float mu = sum * 0.0625f;
        float ss = tt[0] * tt[0] + tt[1] * tt[1] + tt[2] * tt[2] + tt[3] * tt[3];
        ss += __shfl_xor(ss, 16);
        ss += __shfl_xor(ss, 32);
        float var = ss * 0.0625f - mu * mu;
        float rs = rsqrtf(var + 1e-5f);
#pragma unroll
        for (int r = 0; r < 4; ++r) {
          float y = (tt[r] - mu) * rs * gam[r] + bet[r];
          Y_lds[buf][((lq * 4 + r) * 16 + wv) * 36 + c2 * 16 + l15] = f2bf(y);
        }
      }
    }
    if (jt >= 1) {
      // PV for tile jt-1 (Y written by all waves before this iter's barrier)
      short8 yf = *(const short8*)&Y_lds[pbuf][(wv * 16 + l15) * 36 + lq * 8];
      acc0 = MFMA16(yf, v0, acc0);
      acc1 = MFMA16(yf, v1, acc1);
      acc2 = MFMA16(yf, v2, acc2);
      acc3 = MFMA16(yf, v3, acc3);
    }
    kc00 = kn00; kc01 = kn01; kc10 = kn10; kc11 = kn11;
  }
  // epilogue: partial output for this j-half -> atomicAdd (out pre-zeroed)
  float* ob = out + (b * 2048 + i0) * 1024 + wv * 64;
#pragma unroll
  for (int r = 0; r < 4; ++r) {
    float* orow = ob + (lq * 4 + r) * 1024;
    atomicAdd(orow + l15, acc0[r]);
    atomicAdd(orow + 16 + l15, acc1[r]);
    atomicAdd(orow + 32 + l15, acc2[r]);
    atomicAdd(orow + 48 + l15, acc3[r]);
  }
}

// ----------------------------- launcher ------------------------------------
extern "C" void kernel_launch(void* const* d_in, const int* in_sizes, int n_in,
                              void* d_out, int out_size, void* d_ws,
                              size_t ws_size, hipStream_t stream) {
  const float* x = (const float*)d_in[0];
  const float* ctx = (const float*)d_in[1];
  const float* Wq = (const float*)d_in[2];
  const float* Wkv = (const float*)d_in[3];
  const float* Wtalk = (const float*)d_in[4];
  const float* gam = (const float*)d_in[5];
  const float* bet = (const float*)d_in[6];
  float* out = (float*)d_out;

  u16* xb = (u16*)d_ws;            // 4  Mi elems
  u16* cb = xb + 4194304;          // 4  Mi
  u16* wqb = cb + 4194304;         // 1  Mi
  u16* wkvb = wqb + 1048576;       // 2  Mi
  u16* qhb = wkvb + 2097152;       // 4  Mi  [b][h][n][64]
  u16* khb = qhb + 4194304;        // 4  Mi  [b][h][j][64]
  u16* vhb = khb + 4194304;        // 4  Mi  [b][h][j][64]
  u16* vtb = vhb + 4194304;        // 4  Mi  [b][h][d][2048]
  float* lsum = (float*)(vtb + 4194304);  // 64 Ki f32  [b][h][i]

  hipMemsetAsync(lsum, 0, 2 * 16 * 2048 * sizeof(float), stream);
  hipMemsetAsync(out, 0, 2 * 2048 * 1024 * sizeof(float), stream);

  cast_bf16<<<2048, 256, 0, stream>>>(x, xb, 4194304);
  cast_bf16<<<2048, 256, 0, stream>>>(ctx, cb, 4194304);
  cast_bf16<<<512, 256, 0, stream>>>(Wq, wqb, 1048576);
  cast_bf16<<<1024, 256, 0, stream>>>(Wkv, wkvb, 2097152);

  gemm_bt<0><<<dim3(64, 16), 256, 0, stream>>>(xb, wqb, qhb, nullptr);
  gemm_bt<1><<<dim3(64, 32), 256, 0, stream>>>(cb, wkvb, khb, vhb);

  transpose_v<<<dim3(32, 16, 2), 256, 0, stream>>>(vhb, vtb);

  attn_denom<<<dim3(128, 2, 2), 1024, 0, stream>>>(qhb, khb, lsum);
  attn_pass2<<<dim3(128, 2, 2), 1024, 0, stream>>>(qhb, khb, vtb, Wtalk, gam,
                                                   bet, lsum, out);
}

// Round 3
// 617.006 us; speedup vs baseline: 1.4004x; 1.4004x over previous
//
#include <hip/hip_runtime.h>

// ---------------------------------------------------------------------------
// Talking-heads attention, fused. B=2, N=M=2048, D=1024, H=16, dh=64.
// R7: R6's occupancy design (512 blocks, 2/CU, slim regs, gamma/beta folded
// into epilogue via V column-sums) but with a provably race-free attention
// loop: TWO barriers per j-tile, SINGLE P/Y LDS buffers (36.9 KB total).
//   QK+P-write | BARRIER_A | talk+LN(z->regs), PV(jt-1) | BARRIER_B | Y-write
// Every LDS producer/consumer pair is barrier-separated in both directions.
// ---------------------------------------------------------------------------

typedef __attribute__((ext_vector_type(8))) short short8;
typedef __attribute__((ext_vector_type(4))) short short4v;
typedef __attribute__((ext_vector_type(4))) float float4v;
typedef unsigned short u16;

#define MFMA16(a, b, c) __builtin_amdgcn_mfma_f32_16x16x32_bf16((a), (b), (c), 0, 0, 0)
// K=16 talk MFMA: A,B are 4 bf16 (short4v). A[i=l15][k=lq*4+t], B[k][j=l15].
#define MFMA16K16(a, b, c) __builtin_amdgcn_mfma_f32_16x16x16bf16_1k((a), (b), (c), 0, 0, 0)

__device__ inline u16 f2bf(float f) {  // RNE f32->bf16 (inputs finite)
  unsigned u = __float_as_uint(f);
  u += 0x7FFFu + ((u >> 16) & 1u);
  return (u16)(u >> 16);
}
__device__ inline float bf2f(u16 u) {
  return __uint_as_float(((unsigned)u) << 16);
}
__device__ inline float fexp2(float x) { return __builtin_amdgcn_exp2f(x); }

// ---------------------------- cast kernel ----------------------------------
__global__ __launch_bounds__(256) void cast_bf16(const float* __restrict__ in,
                                                 u16* __restrict__ out, int n) {
  int i = (blockIdx.x * 256 + threadIdx.x) * 8;
  if (i + 8 > n) return;
  float4v f0 = *(const float4v*)(in + i);
  float4v f1 = *(const float4v*)(in + i + 4);
  short8 o;
  o[0] = (short)f2bf(f0[0]); o[1] = (short)f2bf(f0[1]);
  o[2] = (short)f2bf(f0[2]); o[3] = (short)f2bf(f0[3]);
  o[4] = (short)f2bf(f1[0]); o[5] = (short)f2bf(f1[1]);
  o[6] = (short)f2bf(f1[2]); o[7] = (short)f2bf(f1[3]);
  *(short8*)(out + i) = o;
}

// ------------------------ projection GEMM ----------------------------------
template <int MODE>
__global__ __launch_bounds__(256, 4) void gemm_bt(const u16* __restrict__ A,
                                                  const u16* __restrict__ W,
                                                  u16* __restrict__ out0,
                                                  u16* __restrict__ out1) {
  __shared__ u16 As[64][40];
  __shared__ u16 Ws[64][40];
  const int t = threadIdx.x;
  const int wave = t >> 6, l = t & 63, l15 = l & 15, lq = l >> 4;
  const int r0 = blockIdx.x * 64, c0 = blockIdx.y * 64;
  const int srow = t >> 2, sch = t & 3;
  const u16* ag = A + (r0 + srow) * 1024 + sch * 8;
  const u16* wg = W + (c0 + srow) * 1024 + sch * 8;

  float4v acc[4];
#pragma unroll
  for (int i = 0; i < 4; ++i) acc[i] = (float4v){0.f, 0.f, 0.f, 0.f};

  short8 av = *(const short8*)ag;
  short8 wv = *(const short8*)wg;
  for (int kt = 0; kt < 32; ++kt) {
    __syncthreads();
    *(short8*)&As[srow][sch * 8] = av;
    *(short8*)&Ws[srow][sch * 8] = wv;
    __syncthreads();
    if (kt < 31) {
      av = *(const short8*)(ag + (kt + 1) * 32);
      wv = *(const short8*)(wg + (kt + 1) * 32);
    }
    short8 af = *(const short8*)&As[wave * 16 + l15][lq * 8];
#pragma unroll
    for (int fn = 0; fn < 4; ++fn) {
      short8 bf = *(const short8*)&Ws[fn * 16 + l15][lq * 8];
      acc[fn] = MFMA16(af, bf, acc[fn]);
    }
  }
#pragma unroll
  for (int fn = 0; fn < 4; ++fn) {
#pragma unroll
    for (int r = 0; r < 4; ++r) {
      int row = r0 + wave * 16 + lq * 4 + r;
      int col = c0 + fn * 16 + l15;
      int b = row >> 11, n = row & 2047;
      float v = acc[fn][r];
      if (MODE == 0) {
        // dh^-0.5 * log2(e): softmax done in base 2 (v_exp_f32 is 2^x)
        v *= 0.125f * 1.44269504088896f;
        int h = col >> 6, d = col & 63;
        out0[(((b * 16 + h) * 2048 + n) << 6) + d] = f2bf(v);
      } else {
        if (col < 1024) {
          int h = col >> 6, d = col & 63;
          out0[(((b * 16 + h) * 2048 + n) << 6) + d] = f2bf(v);
        } else {
          int cc = col - 1024;
          int h = cc >> 6, d = cc & 63;
          out1[(((b * 16 + h) * 2048 + n) << 6) + d] = f2bf(v);
        }
      }
    }
  }
}

// --------------------------- V transpose + column sums ---------------------
// Also accumulates vsum[b][h][jh][d] = sum_{j in half jh} V[b,h,j,d] (f32),
// used to fold LN beta into the attention epilogue.
__global__ __launch_bounds__(256) void transpose_v(const u16* __restrict__ vh,
                                                   u16* __restrict__ vt,
                                                   float* __restrict__ vsum) {
  __shared__ u16 tile[64][72];
  const int t = threadIdx.x;
  const int j0 = blockIdx.x * 64, h = blockIdx.y, b = blockIdx.z;
  const u16* src = vh + (((b * 16 + h) * 2048 + j0) << 6);
  int row = t >> 2, c = t & 3;
  short8 v0 = *(const short8*)(src + row * 64 + c * 8);
  short8 v1 = *(const short8*)(src + row * 64 + (c + 4) * 8);
  *(short8*)&tile[row][c * 8] = v0;
  *(short8*)&tile[row][(c + 4) * 8] = v1;
  __syncthreads();
  int d = t >> 2, jc = t & 3;
  short8 o0, o1;
#pragma unroll
  for (int jj = 0; jj < 8; ++jj) o0[jj] = (short)tile[jc * 16 + jj][d];
#pragma unroll
  for (int jj = 0; jj < 8; ++jj) o1[jj] = (short)tile[jc * 16 + 8 + jj][d];
  u16* dst = vt + ((b * 16 + h) * 64 + d) * 2048 + j0 + jc * 16;
  *(short8*)dst = o0;
  *(short8*)(dst + 8) = o1;
  // column-sum contribution (16 j's per thread)
  float s = 0.f;
#pragma unroll
  for (int jj = 0; jj < 8; ++jj) s += bf2f((u16)o0[jj]) + bf2f((u16)o1[jj]);
  int jh = blockIdx.x >> 4;  // j0 / 1024
  atomicAdd(vsum + ((b * 16 + h) * 2 + jh) * 64 + d, s);
}

// ----------------------- softmax denominators ------------------------------
// grid (itile=128, jhalf=2, b=2) = 512 blocks, 16 waves, NO LDS, no barriers.
// Register-slim: K loaded 2 frags at a time next to its MFMA.
__global__ __launch_bounds__(1024, 8) void attn_denom(
    const u16* __restrict__ qh, const u16* __restrict__ kh,
    float* __restrict__ lsum) {
  const int tid = threadIdx.x;
  const int wv = tid >> 6;  // wave id == head
  const int l = tid & 63, l15 = l & 15, lq = l >> 4;
  const int i0 = blockIdx.x * 16;
  const int jh = blockIdx.y;
  const int b = blockIdx.z;
  const int bh = b * 16 + wv;

  const u16* qbase = qh + ((bh * 2048 + i0) << 6);
  short8 qf0 = *(const short8*)(qbase + l15 * 64 + lq * 8);
  short8 qf1 = *(const short8*)(qbase + l15 * 64 + 32 + lq * 8);
  const u16* kbase = kh + ((bh * 2048 + jh * 1024) << 6);

  float ps0 = 0.f, ps1 = 0.f, ps2 = 0.f, ps3 = 0.f;
  for (int jt = 0; jt < 32; ++jt) {
    const u16* kp = kbase + ((jt * 32) << 6);
    float4v s0 = {0.f, 0.f, 0.f, 0.f}, s1 = {0.f, 0.f, 0.f, 0.f};
    short8 ka = *(const short8*)(kp + l15 * 64 + lq * 8);
    short8 kb = *(const short8*)(kp + l15 * 64 + 32 + lq * 8);
    s0 = MFMA16(qf0, ka, s0);
    s0 = MFMA16(qf1, kb, s0);
    ka = *(const short8*)(kp + (16 + l15) * 64 + lq * 8);
    kb = *(const short8*)(kp + (16 + l15) * 64 + 32 + lq * 8);
    s1 = MFMA16(qf0, ka, s1);
    s1 = MFMA16(qf1, kb, s1);
    ps0 += fexp2(s0[0]) + fexp2(s1[0]);
    ps1 += fexp2(s0[1]) + fexp2(s1[1]);
    ps2 += fexp2(s0[2]) + fexp2(s1[2]);
    ps3 += fexp2(s0[3]) + fexp2(s1[3]);
  }
#pragma unroll
  for (int d = 1; d < 16; d <<= 1) {
    ps0 += __shfl_xor(ps0, d);
    ps1 += __shfl_xor(ps1, d);
    ps2 += __shfl_xor(ps2, d);
    ps3 += __shfl_xor(ps3, d);
  }
  if (l15 == 0) {
    float* lp = lsum + bh * 2048 + i0 + lq * 4;
    atomicAdd(lp + 0, ps0);
    atomicAdd(lp + 1, ps1);
    atomicAdd(lp + 2, ps2);
    atomicAdd(lp + 3, ps3);
  }
}

// ------------------------- fused attention pass 2 --------------------------
// grid (itile=128, jhalf=2, b=2) = 512 blocks, 16 waves (wave == head).
// LDS 36.9 KB single-buffer, 2 barriers/iter (race-free by construction):
//   QK(jt)+P-write | A | talk(jt)->z regs, PV(jt-1) | B | Y-write(jt)
// Register-slim (<=64): K/V loaded beside their MFMAs; LN z kept packed bf16;
// gamma/beta applied in epilogue (beta via V column sums).
__global__ __launch_bounds__(1024, 8) void attn_pass2(
    const u16* __restrict__ qh, const u16* __restrict__ kh,
    const u16* __restrict__ vt, const float* __restrict__ wtalk,
    const float* __restrict__ gamma, const float* __restrict__ beta,
    const float* __restrict__ lsum, const float* __restrict__ vsum,
    float* __restrict__ out) {
  __shared__ u16 P_lds[512 * 18];  // [e=i*32+jl][18]; cols 0..15 used
  __shared__ u16 Y_lds[256 * 36];  // [g*16+i][36];   cols 0..31 used

  const int tid = threadIdx.x;
  const int wv = tid >> 6;  // wave id == head
  const int l = tid & 63, l15 = l & 15, lq = l >> 4;
  const int i0 = blockIdx.x * 16;
  const int jh = blockIdx.y;
  const int b = blockIdx.z;
  const int bh = b * 16 + wv;

  // Wtalk A-fragment for K=16 MFMA: A[g=l15][h=lq*4+t]
  short4v wfrag;
#pragma unroll
  for (int t4 = 0; t4 < 4; ++t4)
    wfrag[t4] = (short)f2bf(wtalk[l15 * 16 + lq * 4 + t4]);

  const u16* qbase = qh + ((bh * 2048 + i0) << 6);
  short8 qf0 = *(const short8*)(qbase + l15 * 64 + lq * 8);
  short8 qf1 = *(const short8*)(qbase + l15 * 64 + 32 + lq * 8);
  const u16* kbase = kh + ((bh * 2048 + jh * 1024) << 6);
  const u16* vbase = vt + (bh * 64) * 2048 + jh * 1024;

  // bias: -log2(denominator), P = 2^(s + bc)
  float bc[4];
#pragma unroll
  for (int r = 0; r < 4; ++r)
    bc[r] = -__builtin_amdgcn_logf(lsum[bh * 2048 + i0 + lq * 4 + r]);

  float4v acc0 = {0.f, 0.f, 0.f, 0.f}, acc1 = acc0, acc2 = acc0, acc3 = acc0;
  short8 zf;  // pending Y(jt) values (bf16), stored after BARRIER_B

  for (int jt = 0; jt <= 32; ++jt) {
    if (jt < 32) {
      // QK for tile jt (K loaded 2 frags at a time), P-write
      const u16* kp = kbase + ((jt * 32) << 6);
      float4v s0 = {0.f, 0.f, 0.f, 0.f}, s1 = {0.f, 0.f, 0.f, 0.f};
      {
        short8 ka = *(const short8*)(kp + l15 * 64 + lq * 8);
        short8 kb = *(const short8*)(kp + l15 * 64 + 32 + lq * 8);
        s0 = MFMA16(qf0, ka, s0);
        s0 = MFMA16(qf1, kb, s0);
        ka = *(const short8*)(kp + (16 + l15) * 64 + lq * 8);
        kb = *(const short8*)(kp + (16 + l15) * 64 + 32 + lq * 8);
        s1 = MFMA16(qf0, ka, s1);
        s1 = MFMA16(qf1, kb, s1);
      }
      // P = 2^(S - log2 l) -> bf16 -> P_lds[e][wv] (stride 18)
      int ebase = lq * 128 + l15;
#pragma unroll
      for (int r = 0; r < 4; ++r) {
        float p0 = fexp2(s0[r] + bc[r]);
        float p1 = fexp2(s1[r] + bc[r]);
        P_lds[(ebase + r * 32) * 18 + wv] = f2bf(p0);
        P_lds[(ebase + r * 32 + 16) * 18 + wv] = f2bf(p1);
      }
    }
    __syncthreads();  // A: P(jt) visible; Y(jt-1) writes (pre-A) visible
    if (jt < 32) {
      // talk (K=16): wave wv covers e in [wv*32, wv*32+32), i.e. i == wv
      float4v t0 = {0.f, 0.f, 0.f, 0.f}, t1 = {0.f, 0.f, 0.f, 0.f};
      {
        const u16* prow = &P_lds[(wv * 32 + l15) * 18 + (lq << 2)];
        union { int i2[2]; short4v s4; } u0, u1;
        u0.i2[0] = *(const int*)(prow);
        u0.i2[1] = *(const int*)(prow + 2);
        u1.i2[0] = *(const int*)(prow + 16 * 18);
        u1.i2[1] = *(const int*)(prow + 16 * 18 + 2);
        t0 = MFMA16K16(wfrag, u0.s4, t0);
        t1 = MFMA16K16(wfrag, u1.s4, t1);
      }
      // head-LN per (i,j) column: z kept in regs until after BARRIER_B
#pragma unroll
      for (int c2 = 0; c2 < 2; ++c2) {
        float4v tt = c2 ? t1 : t0;
        float sum = tt[0] + tt[1] + tt[2] + tt[3];
        sum += __shfl_xor(sum, 16);
        sum += __shfl_xor(sum, 32);
        float mu = sum * 0.0625f;
        float ss = tt[0] * tt[0] + tt[1] * tt[1] + tt[2] * tt[2] + tt[3] * tt[3];
        ss += __shfl_xor(ss, 16);
        ss += __shfl_xor(ss, 32);
        float var = ss * 0.0625f - mu * mu;
        float rs = rsqrtf(var + 1e-5f);
#pragma unroll
        for (int r = 0; r < 4; ++r)
          zf[c2 * 4 + r] = (short)f2bf((tt[r] - mu) * rs);
      }
    }
    if (jt >= 1) {
      // PV for tile jt-1 (Y written before A of this iter, barrier-safe)
      const u16* vp = vbase + (jt - 1) * 32 + lq * 8;
      short8 yf = *(const short8*)&Y_lds[(wv * 16 + l15) * 36 + lq * 8];
      short8 va = *(const short8*)(vp + l15 * 2048);
      short8 vb = *(const short8*)(vp + (16 + l15) * 2048);
      acc0 = MFMA16(yf, va, acc0);
      va = *(const short8*)(vp + (32 + l15) * 2048);
      acc1 = MFMA16(yf, vb, acc1);
      vb = *(const short8*)(vp + (48 + l15) * 2048);
      acc2 = MFMA16(yf, va, acc2);
      acc3 = MFMA16(yf, vb, acc3);
    }
    __syncthreads();  // B: all PV reads of Y(jt-1) complete
    if (jt < 32) {
      // Y-write(jt): safe to overwrite now
#pragma unroll
      for (int c2 = 0; c2 < 2; ++c2)
#pragma unroll
        for (int r = 0; r < 4; ++r)
          Y_lds[((lq * 4 + r) * 16 + wv) * 36 + c2 * 16 + l15] =
              (u16)zf[c2 * 4 + r];
    }
  }
  // epilogue: out_partial = gamma[g]*acc + beta[g]*vsum_half (g == wv)
  const float gamw = gamma[wv], betw = beta[wv];
  const float* vs = vsum + ((b * 16 + wv) * 2 + jh) * 64;
  const float bv0 = betw * vs[l15];
  const float bv1 = betw * vs[16 + l15];
  const float bv2 = betw * vs[32 + l15];
  const float bv3 = betw * vs[48 + l15];
  float* ob = out + (b * 2048 + i0) * 1024 + wv * 64;
#pragma unroll
  for (int r = 0; r < 4; ++r) {
    float* orow = ob + (lq * 4 + r) * 1024;
    atomicAdd(orow + l15, gamw * acc0[r] + bv0);
    atomicAdd(orow + 16 + l15, gamw * acc1[r] + bv1);
    atomicAdd(orow + 32 + l15, gamw * acc2[r] + bv2);
    atomicAdd(orow + 48 + l15, gamw * acc3[r] + bv3);
  }
}

// ----------------------------- launcher ------------------------------------
extern "C" void kernel_launch(void* const* d_in, const int* in_sizes, int n_in,
                              void* d_out, int out_size, void* d_ws,
                              size_t ws_size, hipStream_t stream) {
  const float* x = (const float*)d_in[0];
  const float* ctx = (const float*)d_in[1];
  const float* Wq = (const float*)d_in[2];
  const float* Wkv = (const float*)d_in[3];
  const float* Wtalk = (const float*)d_in[4];
  const float* gam = (const float*)d_in[5];
  const float* bet = (const float*)d_in[6];
  float* out = (float*)d_out;

  u16* xb = (u16*)d_ws;            // 4  Mi elems
  u16* cb = xb + 4194304;          // 4  Mi
  u16* wqb = cb + 4194304;         // 1  Mi
  u16* wkvb = wqb + 1048576;       // 2  Mi
  u16* qhb = wkvb + 2097152;       // 4  Mi  [b][h][n][64]
  u16* khb = qhb + 4194304;        // 4  Mi  [b][h][j][64]
  u16* vhb = khb + 4194304;        // 4  Mi  [b][h][j][64]
  u16* vtb = vhb + 4194304;        // 4  Mi  [b][h][d][2048]
  float* lsum = (float*)(vtb + 4194304);  // 64 Ki f32  [b][h][i]
  float* vsum = lsum + 65536;             // 4 Ki f32   [b][h][jh][d]

  hipMemsetAsync(lsum, 0, 65536 * sizeof(float), stream);
  hipMemsetAsync(vsum, 0, 4096 * sizeof(float), stream);
  hipMemsetAsync(out, 0, 2 * 2048 * 1024 * sizeof(float), stream);

  cast_bf16<<<2048, 256, 0, stream>>>(x, xb, 4194304);
  cast_bf16<<<2048, 256, 0, stream>>>(ctx, cb, 4194304);
  cast_bf16<<<512, 256, 0, stream>>>(Wq, wqb, 1048576);
  cast_bf16<<<1024, 256, 0, stream>>>(Wkv, wkvb, 2097152);

  gemm_bt<0><<<dim3(64, 16), 256, 0, stream>>>(xb, wqb, qhb, nullptr);
  gemm_bt<1><<<dim3(64, 32), 256, 0, stream>>>(cb, wkvb, khb, vhb);

  transpose_v<<<dim3(32, 16, 2), 256, 0, stream>>>(vhb, vtb, vsum);

  attn_denom<<<dim3(128, 2, 2), 1024, 0, stream>>>(qhb, khb, lsum);
  attn_pass2<<<dim3(128, 2, 2), 1024, 0, stream>>>(qhb, khb, vtb, Wtalk, gam,
                                                   bet, lsum, vsum, out);
}